// Round 15
// baseline (209.482 us; speedup 1.0000x reference)
//
#include <hip/hip_runtime.h>

#define H_ 56
#define W_ 56
#define HW_ 3136
#define CIN_ 256
#define COUT_ 256

typedef __attribute__((ext_vector_type(8))) short short8;
typedef __attribute__((ext_vector_type(4))) float f32x4;

// Pre-swizzled bf16 weights, written by prep_weights each launch (idempotent).
// Layout: [kt][e], e = m*32 + col (m 0..255), content =
//   bf16(W[m][kt*32 + (col ^ swz32(m))])
__device__ unsigned short g_wbf[COUT_ * CIN_];

__device__ __forceinline__ int swz32(int n) { return ((n ^ (n >> 3)) & 3) << 3; }

__device__ __forceinline__ unsigned short f2bf(float f) {
  union { float f; unsigned int i; } v; v.f = f;
  unsigned int b = v.i + (0x7fffu + ((v.i >> 16) & 1u));  // RNE
  return (unsigned short)(b >> 16);
}

__device__ __forceinline__ void gload_lds16(const unsigned short* g, unsigned short* l) {
  __builtin_amdgcn_global_load_lds(
      (const __attribute__((address_space(1))) unsigned int*)g,
      (__attribute__((address_space(3))) unsigned int*)l, 16, 0, 0);
}

__device__ __forceinline__ void shift_decode(int c, int& dx, int& dy) {
  if (c < 102)      { dy = 0; dx = (c < 51) ? 0 : 1; }
  else if (c < 153) { dx = -1; dy = 0; }
  else if (c < 204) { dx = 0;  dy = 1; }
  else              { dx = 0;  dy = -1; }
}

__global__ __launch_bounds__(256)
void prep_weights(const float* __restrict__ wgt) {
  int idx = blockIdx.x * 256 + threadIdx.x;   // 0..65535
  int kt  = idx >> 13;                        // 0..7
  int e   = idx & 8191;
  int m   = e >> 5, col = e & 31;             // m 0..255
  int k   = kt * 32 + (col ^ swz32(m));
  g_wbf[idx] = f2bf(wgt[m * CIN_ + k]);
}

// Load next x slice into registers (shift applied later at LDS-write time).
__device__ __forceinline__ void load_x(const float* __restrict__ x, size_t xb,
                                       int hh, int w0, int c,
                                       float4& p0, float4& p1, float& pe) {
  int dx, dy; shift_decode(c, dx, dy);
  int h2 = hh - dy;
  p0 = make_float4(0.f, 0.f, 0.f, 0.f);
  p1 = make_float4(0.f, 0.f, 0.f, 0.f);
  pe = 0.f;
  if ((unsigned)h2 < (unsigned)H_) {
    const float* row = x + xb + (size_t)c * HW_ + h2 * W_;
    p0 = *(const float4*)(row + w0);
    p1 = *(const float4*)(row + w0 + 4);
    if (dx == 1)       { if (w0 > 0)      pe = row[w0 - 1]; }
    else if (dx == -1) { if (w0 + 8 < W_) pe = row[w0 + 8]; }
  }
}

// Apply the W-shift in registers and scatter bf16 into the (transposed) B tile.
__device__ __forceinline__ void write_b(unsigned short* __restrict__ B,
                                        int nloc0, int krow, int c,
                                        const float4& p0, const float4& p1, float pe) {
  int dx, dy; shift_decode(c, dx, dy);
  float s[8] = {p0.x, p0.y, p0.z, p0.w, p1.x, p1.y, p1.z, p1.w};
  float vals[8];
  if (dx == 0) {
    #pragma unroll
    for (int i = 0; i < 8; ++i) vals[i] = s[i];
  } else if (dx == 1) {          // y[w] = x[w-1]
    #pragma unroll
    for (int i = 7; i >= 1; --i) vals[i] = s[i - 1];
    vals[0] = pe;
  } else {                       // dx == -1: y[w] = x[w+1]
    #pragma unroll
    for (int i = 0; i < 7; ++i) vals[i] = s[i + 1];
    vals[7] = pe;
  }
  #pragma unroll
  for (int i = 0; i < 8; ++i) {
    int nl = nloc0 + i;
    B[nl * 32 + (krow ^ swz32(nl))] = f2bf(vals[i]);
  }
}

__global__ __launch_bounds__(512, 2)
void shiftconv_gemm(const float* __restrict__ x,
                    const float* __restrict__ gamma,
                    const float* __restrict__ beta,
                    const float* __restrict__ rmean,
                    const float* __restrict__ rvar,
                    float* __restrict__ out)
{
  // ONLY structural change vs R14 (70.8 us): BN 64 -> 128 (512 thr, 8 waves,
  // same 64o x 64n per-wave tile). Halves block count -> W restage demand
  // 200 -> 100 MB per dispatch and halves per-dispatch barrier-tiles.
  __shared__ unsigned short Alds[2][256 * 32];   // 2 x 16 KB
  __shared__ unsigned short Blds[2][128 * 32];   // 2 x 8 KB
  __shared__ float bnp[512];                     // interleaved (inv, add), 256 o

  const int t = threadIdx.x;
  // XCD swizzle: nwg = 784 = 8*98, bijective chunked mapping (verified lever).
  const int orig = blockIdx.x;
  const int bn   = (orig & 7) * 98 + (orig >> 3);   // 784 n-tiles of 128

  const int lane = t & 63;
  const int wv   = t >> 6;       // 8 waves
  const int wo   = wv >> 1;      // wave o-quarter (64 of 256)
  const int wn   = wv & 1;       // wave n-half (64 of 128)
  const int quad = lane >> 4;
  const int l15  = lane & 15;

  if (t < 256) {
    int o = t;
    float inv = gamma[o] * rsqrtf(rvar[o] + 1e-5f);
    bnp[2 * t]     = inv;
    bnp[2 * t + 1] = beta[o] - rmean[o] * inv;
  }

  // ---- B staging decode (constant across K loop): 8 n x 1 k per thread ----
  const int chunk  = t & 15;          // 16 chunks of 8 n = 128 n
  const int krow   = t >> 4;          // 0..31 = k within tile
  const int nloc0  = chunk * 8;
  const int nglob0 = bn * 128 + nloc0;
  const int bidx   = nglob0 / HW_;    // 8-n chunks never straddle an image
  const int rem    = nglob0 - bidx * HW_;
  const int hh     = rem / W_;
  const int w0     = rem - hh * W_;   // multiple of 8
  const size_t xb  = (size_t)bidx * CIN_ * HW_;

  // ---- A staging source: pre-swizzled bf16 weights ----
  const unsigned short* wsrc = g_wbf + t * 8;

  f32x4 acc[4][4];
  #pragma unroll
  for (int i = 0; i < 4; ++i)
    #pragma unroll
    for (int j = 0; j < 4; ++j)
      acc[i][j] = (f32x4){0.f, 0.f, 0.f, 0.f};

  float4 p0, p1;   // raw prefetched x (shift applied at write time)
  float  pe;       // edge element for dx = +/-1

  // ---- prologue: stage tile 0 (A = 16 KB: 2 gload rounds of 8 KB) ----
  {
    unsigned short* l = &Alds[0][t * 8];
    gload_lds16(wsrc,        l);
    gload_lds16(wsrc + 4096, l + 4096);
  }
  load_x(x, xb, hh, w0, krow, p0, p1, pe);
  write_b(&Blds[0][0], nloc0, krow, krow, p0, p1, pe);
  __syncthreads();

  const int kb = quad * 8;
  int buf = 0;

  // ---- main loop: one barrier per K-tile; next tile's loads in flight ----
  for (int kt = 0; kt < 8; ++kt) {
    if (kt < 7) {
      const unsigned short* g = wsrc + (kt + 1) * 8192;
      unsigned short* l = &Alds[buf ^ 1][t * 8];
      gload_lds16(g,        l);
      gload_lds16(g + 4096, l + 4096);
      load_x(x, xb, hh, w0, (kt + 1) * 32 + krow, p0, p1, pe);
    }

    short8 af[4], bfr[4];
    #pragma unroll
    for (int f = 0; f < 4; ++f) {
      int ml = wo * 64 + f * 16 + l15;
      af[f] = *(const short8*)(&Alds[buf][ml * 32 + (kb ^ swz32(ml))]);
    }
    #pragma unroll
    for (int g2 = 0; g2 < 4; ++g2) {
      int nl2 = wn * 64 + g2 * 16 + l15;
      bfr[g2] = *(const short8*)(&Blds[buf][nl2 * 32 + (kb ^ swz32(nl2))]);
    }
    #pragma unroll
    for (int mf = 0; mf < 4; ++mf)
      #pragma unroll
      for (int nf = 0; nf < 4; ++nf)
        acc[mf][nf] = __builtin_amdgcn_mfma_f32_16x16x32_bf16(
            af[mf], bfr[nf], acc[mf][nf], 0, 0, 0);

    if (kt < 7)
      write_b(&Blds[buf ^ 1][0], nloc0, krow, (kt + 1) * 32 + krow, p0, p1, pe);

    __syncthreads();
    buf ^= 1;
  }

  // ---- epilogue: BN + ReLU + fp32 store ----
  size_t nbase[4];
  #pragma unroll
  for (int nf = 0; nf < 4; ++nf) {
    int ng  = bn * 128 + wn * 64 + nf * 16 + l15;
    int b2  = ng / HW_;
    int hw2 = ng - b2 * HW_;
    nbase[nf] = (size_t)b2 * COUT_ * HW_ + hw2;
  }
  #pragma unroll
  for (int mf = 0; mf < 4; ++mf) {
    int mloc = wo * 64 + mf * 16 + quad * 4;   // global o for reg r=0
    float inv[4], add[4];
    #pragma unroll
    for (int r = 0; r < 4; ++r) {
      inv[r] = bnp[2 * (mloc + r)];
      add[r] = bnp[2 * (mloc + r) + 1];
    }
    size_t obase = (size_t)mloc * HW_;
    #pragma unroll
    for (int nf = 0; nf < 4; ++nf) {
      #pragma unroll
      for (int r = 0; r < 4; ++r) {
        float v = fmaf(acc[mf][nf][r], inv[r], add[r]);
        out[nbase[nf] + obase + (size_t)r * HW_] = fmaxf(v, 0.0f);
      }
    }
  }
}

extern "C" void kernel_launch(void* const* d_in, const int* in_sizes, int n_in,
                              void* d_out, int out_size, void* d_ws, size_t ws_size,
                              hipStream_t stream) {
  const float* x     = (const float*)d_in[0];
  const float* wgt   = (const float*)d_in[1];
  const float* gamma = (const float*)d_in[2];
  const float* beta  = (const float*)d_in[3];
  const float* rmean = (const float*)d_in[4];
  const float* rvar  = (const float*)d_in[5];
  float* out = (float*)d_out;

  prep_weights<<<dim3(256), dim3(256), 0, stream>>>(wgt);
  shiftconv_gemm<<<dim3(784), dim3(512), 0, stream>>>(x, gamma, beta, rmean, rvar, out);
}